// Round 1
// baseline (12760.811 us; speedup 1.0000x reference)
//
#include <hip/hip_runtime.h>

#define N_USERS 200000
#define N_ITEMS 100000
#define N_NODES 300000   // N_USERS + N_ITEMS
#define DIM 64
#define N_EDGES 5000000

// ---------------------------------------------------------------------------
// init: A = concat(user, item); out = same (layer-0 contribution to acc)
// ---------------------------------------------------------------------------
__global__ void init_concat(const float4* __restrict__ user,
                            const float4* __restrict__ item,
                            float4* __restrict__ A,
                            float4* __restrict__ out) {
    int i = blockIdx.x * blockDim.x + threadIdx.x;
    const int n = N_NODES * (DIM / 4);
    if (i >= n) return;
    const int userN = N_USERS * (DIM / 4);
    float4 v = (i < userN) ? user[i] : item[i - userN];
    A[i] = v;
    out[i] = v;
}

// ---------------------------------------------------------------------------
// scatter: dst[row] += src[col] * w   (dst pre-zeroed)
// 16 lanes per edge; lane l handles float4 chunk l (dims 4l..4l+3).
// Gather read per edge = one contiguous 256B segment (coalesced).
// ---------------------------------------------------------------------------
__global__ void scatter_edges(const float4* __restrict__ src,
                              float* __restrict__ dst,
                              const int* __restrict__ rows,
                              const int* __restrict__ cols,
                              const float* __restrict__ w) {
    long long t = (long long)blockIdx.x * blockDim.x + threadIdx.x;
    long long e = t >> 4;
    int lane = (int)(t & 15);
    if (e >= N_EDGES) return;

    int r = rows[e];
    int c = cols[e];
    float wt = w[e];

    float4 v = src[c * (DIM / 4) + lane];
    float* d = dst + (long long)r * DIM + lane * 4;
    atomicAdd(d + 0, v.x * wt);
    atomicAdd(d + 1, v.y * wt);
    atomicAdd(d + 2, v.z * wt);
    atomicAdd(d + 3, v.w * wt);
}

// ---------------------------------------------------------------------------
// acc update: out = (out + B) * scale   (scale=1 mid-layers, 0.25 final)
// ---------------------------------------------------------------------------
__global__ void add_acc(float4* __restrict__ out,
                        const float4* __restrict__ B,
                        float scale) {
    int i = blockIdx.x * blockDim.x + threadIdx.x;
    const int n = N_NODES * (DIM / 4);
    if (i >= n) return;
    float4 a = out[i];
    float4 b = B[i];
    a.x = (a.x + b.x) * scale;
    a.y = (a.y + b.y) * scale;
    a.z = (a.z + b.z) * scale;
    a.w = (a.w + b.w) * scale;
    out[i] = a;
}

extern "C" void kernel_launch(void* const* d_in, const int* in_sizes, int n_in,
                              void* d_out, int out_size, void* d_ws, size_t ws_size,
                              hipStream_t stream) {
    const float* user_w = (const float*)d_in[0];
    const float* item_w = (const float*)d_in[1];
    const int*   eidx   = (const int*)d_in[2];
    const float* ew     = (const float*)d_in[3];

    const int* rows = eidx;             // edge_index[0]
    const int* cols = eidx + N_EDGES;   // edge_index[1]

    float* out = (float*)d_out;
    float* A = (float*)d_ws;
    float* B = A + (size_t)N_NODES * DIM;
    const size_t buf_bytes = (size_t)N_NODES * DIM * sizeof(float);

    const int nvec = N_NODES * (DIM / 4);
    const int vec_blocks = (nvec + 255) / 256;

    const long long scatter_threads = (long long)N_EDGES * 16;
    const int scatter_blocks = (int)((scatter_threads + 255) / 256);

    // B = 0; A = concat(user,item); out = A
    hipMemsetAsync(B, 0, buf_bytes, stream);
    init_concat<<<vec_blocks, 256, 0, stream>>>(
        (const float4*)user_w, (const float4*)item_w, (float4*)A, (float4*)out);

    // layer 1: A -> B ; out += B
    scatter_edges<<<scatter_blocks, 256, 0, stream>>>((const float4*)A, B, rows, cols, ew);
    add_acc<<<vec_blocks, 256, 0, stream>>>((float4*)out, (const float4*)B, 1.0f);

    // layer 2: B -> A ; out += A
    hipMemsetAsync(A, 0, buf_bytes, stream);
    scatter_edges<<<scatter_blocks, 256, 0, stream>>>((const float4*)B, A, rows, cols, ew);
    add_acc<<<vec_blocks, 256, 0, stream>>>((float4*)out, (const float4*)A, 1.0f);

    // layer 3: A -> B ; out = (out + B) / 4
    hipMemsetAsync(B, 0, buf_bytes, stream);
    scatter_edges<<<scatter_blocks, 256, 0, stream>>>((const float4*)A, B, rows, cols, ew);
    add_acc<<<vec_blocks, 256, 0, stream>>>((float4*)out, (const float4*)B, 0.25f);
}

// Round 2
// 1330.725 us; speedup vs baseline: 9.5894x; 9.5894x over previous
//
#include <hip/hip_runtime.h>

#define N_USERS 200000
#define N_ITEMS 100000
#define N_NODES 300000   // N_USERS + N_ITEMS
#define DIM 64
#define N_EDGES 5000000
#define NBLK ((N_NODES + 255) / 256)   // 1172 scan blocks

// ---------------------------------------------------------------------------
// init: A = concat(user, item); out = same (layer-0 contribution to acc)
// ---------------------------------------------------------------------------
__global__ void init_concat(const float4* __restrict__ user,
                            const float4* __restrict__ item,
                            float4* __restrict__ A,
                            float4* __restrict__ out) {
    int i = blockIdx.x * blockDim.x + threadIdx.x;
    const int n = N_NODES * (DIM / 4);
    if (i >= n) return;
    const int userN = N_USERS * (DIM / 4);
    float4 v = (i < userN) ? user[i] : item[i - userN];
    A[i] = v;
    out[i] = v;
}

// ---------------------------------------------------------------------------
// CSR build step 1: histogram of destination rows
// ---------------------------------------------------------------------------
__global__ void hist_rows(const int* __restrict__ rows, int* __restrict__ counts) {
    int e = blockIdx.x * blockDim.x + threadIdx.x;
    if (e < N_EDGES) atomicAdd(&counts[rows[e]], 1);
}

// ---------------------------------------------------------------------------
// CSR build step 2a: per-block exclusive scan (256 elems/block).
// Writes exclusive-within-block into row_ptr, block total into bsums.
// ---------------------------------------------------------------------------
__global__ void scan_block(const int* __restrict__ counts,
                           int* __restrict__ row_ptr,
                           int* __restrict__ bsums) {
    __shared__ int s[256];
    int i = blockIdx.x * 256 + threadIdx.x;
    int v = (i < N_NODES) ? counts[i] : 0;
    s[threadIdx.x] = v;
    __syncthreads();
    for (int off = 1; off < 256; off <<= 1) {
        int t = (threadIdx.x >= off) ? s[threadIdx.x - off] : 0;
        __syncthreads();
        s[threadIdx.x] += t;
        __syncthreads();
    }
    if (i < N_NODES) row_ptr[i] = s[threadIdx.x] - v;   // exclusive
    if (threadIdx.x == 255) bsums[blockIdx.x] = s[255]; // block total
}

// ---------------------------------------------------------------------------
// CSR build step 2b: single-block exclusive scan of the block sums
// ---------------------------------------------------------------------------
__global__ void scan_sums(int* __restrict__ bsums, int nb) {
    __shared__ int s[256];
    __shared__ int carry;
    if (threadIdx.x == 0) carry = 0;
    __syncthreads();
    for (int base = 0; base < nb; base += 256) {
        int i = base + threadIdx.x;
        int v = (i < nb) ? bsums[i] : 0;
        s[threadIdx.x] = v;
        __syncthreads();
        for (int off = 1; off < 256; off <<= 1) {
            int t = (threadIdx.x >= off) ? s[threadIdx.x - off] : 0;
            __syncthreads();
            s[threadIdx.x] += t;
            __syncthreads();
        }
        if (i < nb) bsums[i] = carry + s[threadIdx.x] - v;  // exclusive
        __syncthreads();
        if (threadIdx.x == 255) carry += s[255];
        __syncthreads();
    }
}

// ---------------------------------------------------------------------------
// CSR build step 2c: add block offsets; init cursor; set sentinel
// ---------------------------------------------------------------------------
__global__ void finalize_rowptr(int* __restrict__ row_ptr,
                                const int* __restrict__ bsums,
                                int* __restrict__ cursor) {
    int i = blockIdx.x * 256 + threadIdx.x;
    if (i < N_NODES) {
        int v = row_ptr[i] + bsums[blockIdx.x];
        row_ptr[i] = v;
        cursor[i] = v;
    }
    if (i == 0) row_ptr[N_NODES] = N_EDGES;
}

// ---------------------------------------------------------------------------
// CSR build step 3: fill col/weight arrays sorted by destination row
// ---------------------------------------------------------------------------
__global__ void fill_csr(const int* __restrict__ rows,
                         const int* __restrict__ cols,
                         const float* __restrict__ w,
                         int* __restrict__ cursor,
                         int* __restrict__ col_s,
                         float* __restrict__ w_s) {
    int e = blockIdx.x * blockDim.x + threadIdx.x;
    if (e >= N_EDGES) return;
    int r = rows[e];
    int pos = atomicAdd(&cursor[r], 1);
    col_s[pos] = cols[e];
    w_s[pos]   = w[e];
}

// ---------------------------------------------------------------------------
// pull layer: one wave per node, lane = dim.
//   dst[node][lane] = sum_e w_e * src[col_e][lane]
//   out[node][lane] = (out[node][lane] + dst_val) * scale
// No atomics; src gathers are 256B coalesced per edge; col/w reads are
// wave-uniform (single request, broadcast).
// ---------------------------------------------------------------------------
__global__ void pull_layer(const float* __restrict__ src,
                           float* __restrict__ dst,
                           float* __restrict__ out,
                           const int* __restrict__ row_ptr,
                           const int* __restrict__ col_s,
                           const float* __restrict__ w_s,
                           float scale) {
    int node = blockIdx.x * (blockDim.x >> 6) + (threadIdx.x >> 6);
    int lane = threadIdx.x & 63;
    if (node >= N_NODES) return;

    int beg = row_ptr[node];
    int end = row_ptr[node + 1];

    float acc = 0.0f;
    int p = beg;
    // unroll-4 to keep multiple gathers in flight
    for (; p + 3 < end; p += 4) {
        int   c0 = col_s[p],     c1 = col_s[p + 1];
        int   c2 = col_s[p + 2], c3 = col_s[p + 3];
        float w0 = w_s[p],       w1 = w_s[p + 1];
        float w2 = w_s[p + 2],   w3 = w_s[p + 3];
        float v0 = src[(size_t)c0 * DIM + lane];
        float v1 = src[(size_t)c1 * DIM + lane];
        float v2 = src[(size_t)c2 * DIM + lane];
        float v3 = src[(size_t)c3 * DIM + lane];
        acc += w0 * v0;
        acc += w1 * v1;
        acc += w2 * v2;
        acc += w3 * v3;
    }
    for (; p < end; ++p) {
        acc += w_s[p] * src[(size_t)col_s[p] * DIM + lane];
    }

    size_t oi = (size_t)node * DIM + lane;
    dst[oi] = acc;
    out[oi] = (out[oi] + acc) * scale;
}

extern "C" void kernel_launch(void* const* d_in, const int* in_sizes, int n_in,
                              void* d_out, int out_size, void* d_ws, size_t ws_size,
                              hipStream_t stream) {
    const float* user_w = (const float*)d_in[0];
    const float* item_w = (const float*)d_in[1];
    const int*   eidx   = (const int*)d_in[2];
    const float* ew     = (const float*)d_in[3];

    const int* rows = eidx;             // edge_index[0] (destination)
    const int* cols = eidx + N_EDGES;   // edge_index[1] (source)

    float* out = (float*)d_out;

    // workspace layout
    float* A       = (float*)d_ws;                       // 19.2M f32
    float* B       = A + (size_t)N_NODES * DIM;          // 19.2M f32
    int*   col_s   = (int*)(B + (size_t)N_NODES * DIM);  // 5M int
    float* w_s     = (float*)(col_s + N_EDGES);          // 5M f32
    int*   row_ptr = (int*)(w_s + N_EDGES);              // N_NODES+1
    int*   cursor  = row_ptr + (N_NODES + 1);            // N_NODES
    int*   counts  = cursor + N_NODES;                   // N_NODES
    int*   bsums   = counts + N_NODES;                   // NBLK

    const int edge_blocks = (N_EDGES + 255) / 256;
    const int node_vec_blocks = (N_NODES * (DIM / 4) + 255) / 256;
    const int pull_blocks = (N_NODES + 3) / 4;           // 4 waves/block

    // ---- build CSR ----
    hipMemsetAsync(counts, 0, (size_t)N_NODES * sizeof(int), stream);
    hist_rows<<<edge_blocks, 256, 0, stream>>>(rows, counts);
    scan_block<<<NBLK, 256, 0, stream>>>(counts, row_ptr, bsums);
    scan_sums<<<1, 256, 0, stream>>>(bsums, NBLK);
    finalize_rowptr<<<NBLK, 256, 0, stream>>>(row_ptr, bsums, cursor);
    fill_csr<<<edge_blocks, 256, 0, stream>>>(rows, cols, ew, cursor, col_s, w_s);

    // ---- init: A = concat(user,item), out = A ----
    init_concat<<<node_vec_blocks, 256, 0, stream>>>(
        (const float4*)user_w, (const float4*)item_w, (float4*)A, (float4*)out);

    // ---- 3 propagation layers, pull-based, acc fused ----
    pull_layer<<<pull_blocks, 256, 0, stream>>>(A, B, out, row_ptr, col_s, w_s, 1.0f);
    pull_layer<<<pull_blocks, 256, 0, stream>>>(B, A, out, row_ptr, col_s, w_s, 1.0f);
    pull_layer<<<pull_blocks, 256, 0, stream>>>(A, B, out, row_ptr, col_s, w_s, 0.25f);
}

// Round 3
// 1213.183 us; speedup vs baseline: 10.5185x; 1.0969x over previous
//
#include <hip/hip_runtime.h>
#include <hip/hip_fp16.h>

#define N_USERS 200000
#define N_ITEMS 100000
#define N_NODES 300000   // N_USERS + N_ITEMS
#define DIM 64
#define N_EDGES 5000000
#define NBLK ((N_NODES + 255) / 256)   // scan blocks

// ---------------------------------------------------------------------------
// CSR build step 1: histogram of destination rows
// ---------------------------------------------------------------------------
__global__ void hist_rows(const int* __restrict__ rows, int* __restrict__ counts) {
    int e = blockIdx.x * blockDim.x + threadIdx.x;
    if (e < N_EDGES) atomicAdd(&counts[rows[e]], 1);
}

// ---------------------------------------------------------------------------
// CSR build step 2a: per-block exclusive scan (256 elems/block)
// ---------------------------------------------------------------------------
__global__ void scan_block(const int* __restrict__ counts,
                           int* __restrict__ row_ptr,
                           int* __restrict__ bsums) {
    __shared__ int s[256];
    int i = blockIdx.x * 256 + threadIdx.x;
    int v = (i < N_NODES) ? counts[i] : 0;
    s[threadIdx.x] = v;
    __syncthreads();
    for (int off = 1; off < 256; off <<= 1) {
        int t = (threadIdx.x >= off) ? s[threadIdx.x - off] : 0;
        __syncthreads();
        s[threadIdx.x] += t;
        __syncthreads();
    }
    if (i < N_NODES) row_ptr[i] = s[threadIdx.x] - v;   // exclusive
    if (threadIdx.x == 255) bsums[blockIdx.x] = s[255]; // block total
}

// ---------------------------------------------------------------------------
// CSR build step 2b: single-block exclusive scan of the block sums
// ---------------------------------------------------------------------------
__global__ void scan_sums(int* __restrict__ bsums, int nb) {
    __shared__ int s[256];
    __shared__ int carry;
    if (threadIdx.x == 0) carry = 0;
    __syncthreads();
    for (int base = 0; base < nb; base += 256) {
        int i = base + threadIdx.x;
        int v = (i < nb) ? bsums[i] : 0;
        s[threadIdx.x] = v;
        __syncthreads();
        for (int off = 1; off < 256; off <<= 1) {
            int t = (threadIdx.x >= off) ? s[threadIdx.x - off] : 0;
            __syncthreads();
            s[threadIdx.x] += t;
            __syncthreads();
        }
        if (i < nb) bsums[i] = carry + s[threadIdx.x] - v;  // exclusive
        __syncthreads();
        if (threadIdx.x == 255) carry += s[255];
        __syncthreads();
    }
}

// ---------------------------------------------------------------------------
// CSR build step 2c: add block offsets; init cursor; set sentinel
// ---------------------------------------------------------------------------
__global__ void finalize_rowptr(int* __restrict__ row_ptr,
                                const int* __restrict__ bsums,
                                int* __restrict__ cursor) {
    int i = blockIdx.x * 256 + threadIdx.x;
    if (i < N_NODES) {
        int v = row_ptr[i] + bsums[blockIdx.x];
        row_ptr[i] = v;
        cursor[i] = v;
    }
    if (i == 0) row_ptr[N_NODES] = N_EDGES;
}

// ---------------------------------------------------------------------------
// CSR build step 3: fill packed (col, weight) entries, one 8B store per edge
// ---------------------------------------------------------------------------
__global__ void fill_csr(const int* __restrict__ rows,
                         const int* __restrict__ cols,
                         const float* __restrict__ w,
                         int* __restrict__ cursor,
                         uint2* __restrict__ entries) {
    int e = blockIdx.x * blockDim.x + threadIdx.x;
    if (e >= N_EDGES) return;
    int r = rows[e];
    int pos = atomicAdd(&cursor[r], 1);
    entries[pos] = make_uint2((unsigned)cols[e], __float_as_uint(w[e]));
}

// ---------------------------------------------------------------------------
// init: A16 = fp16(concat(user,item)) — 4 f32 -> 4 f16 (8B store) per thread
// ---------------------------------------------------------------------------
__global__ void init_f16(const float4* __restrict__ user,
                         const float4* __restrict__ item,
                         uint2* __restrict__ A16) {
    int i = blockIdx.x * blockDim.x + threadIdx.x;
    const int n = N_NODES * (DIM / 4);
    if (i >= n) return;
    const int userN = N_USERS * (DIM / 4);
    float4 v = (i < userN) ? user[i] : item[i - userN];
    __half2 h01 = __floats2half2_rn(v.x, v.y);
    __half2 h23 = __floats2half2_rn(v.z, v.w);
    uint2 st;
    st.x = *reinterpret_cast<unsigned*>(&h01);
    st.y = *reinterpret_cast<unsigned*>(&h23);
    A16[i] = st;
}

// ---------------------------------------------------------------------------
// pull layer (fp16 src/dst): one wave per node, lane = dim.
//   dst[node][lane] = f16( sum_e w_e * f32(src[col_e][lane]) )
// Gather per edge = one contiguous 128B segment. Entry read is wave-uniform.
// ---------------------------------------------------------------------------
__global__ void pull16(const __half* __restrict__ src,
                       __half* __restrict__ dst,
                       const int* __restrict__ row_ptr,
                       const uint2* __restrict__ entries) {
    int node = blockIdx.x * (blockDim.x >> 6) + (threadIdx.x >> 6);
    int lane = threadIdx.x & 63;
    if (node >= N_NODES) return;

    int beg = row_ptr[node];
    int end = row_ptr[node + 1];

    float acc = 0.0f;
    int p = beg;
    for (; p + 3 < end; p += 4) {
        uint2 e0 = entries[p],     e1 = entries[p + 1];
        uint2 e2 = entries[p + 2], e3 = entries[p + 3];
        float v0 = __half2float(src[(size_t)e0.x * DIM + lane]);
        float v1 = __half2float(src[(size_t)e1.x * DIM + lane]);
        float v2 = __half2float(src[(size_t)e2.x * DIM + lane]);
        float v3 = __half2float(src[(size_t)e3.x * DIM + lane]);
        acc = fmaf(__uint_as_float(e0.y), v0, acc);
        acc = fmaf(__uint_as_float(e1.y), v1, acc);
        acc = fmaf(__uint_as_float(e2.y), v2, acc);
        acc = fmaf(__uint_as_float(e3.y), v3, acc);
    }
    for (; p < end; ++p) {
        uint2 e0 = entries[p];
        float v0 = __half2float(src[(size_t)e0.x * DIM + lane]);
        acc = fmaf(__uint_as_float(e0.y), v0, acc);
    }

    dst[(size_t)node * DIM + lane] = __float2half_rn(acc);
}

// ---------------------------------------------------------------------------
// final: out = (concat(user,item) + L1 + L2 + L3) * 0.25   (f32 out)
// ---------------------------------------------------------------------------
__device__ __forceinline__ float2 h2f2(unsigned u) {
    __half2 h = *reinterpret_cast<__half2*>(&u);
    return __half22float2(h);
}

__global__ void final_combine(const float4* __restrict__ user,
                              const float4* __restrict__ item,
                              const uint2* __restrict__ L1,
                              const uint2* __restrict__ L2,
                              const uint2* __restrict__ L3,
                              float4* __restrict__ out) {
    int i = blockIdx.x * blockDim.x + threadIdx.x;
    const int n = N_NODES * (DIM / 4);
    if (i >= n) return;
    const int userN = N_USERS * (DIM / 4);
    float4 v = (i < userN) ? user[i] : item[i - userN];

    uint2 a = L1[i], b = L2[i], c = L3[i];
    float2 a01 = h2f2(a.x), a23 = h2f2(a.y);
    float2 b01 = h2f2(b.x), b23 = h2f2(b.y);
    float2 c01 = h2f2(c.x), c23 = h2f2(c.y);

    v.x = (v.x + a01.x + b01.x + c01.x) * 0.25f;
    v.y = (v.y + a01.y + b01.y + c01.y) * 0.25f;
    v.z = (v.z + a23.x + b23.x + c23.x) * 0.25f;
    v.w = (v.w + a23.y + b23.y + c23.y) * 0.25f;
    out[i] = v;
}

extern "C" void kernel_launch(void* const* d_in, const int* in_sizes, int n_in,
                              void* d_out, int out_size, void* d_ws, size_t ws_size,
                              hipStream_t stream) {
    const float* user_w = (const float*)d_in[0];
    const float* item_w = (const float*)d_in[1];
    const int*   eidx   = (const int*)d_in[2];
    const float* ew     = (const float*)d_in[3];

    const int* rows = eidx;             // edge_index[0] (destination)
    const int* cols = eidx + N_EDGES;   // edge_index[1] (source)

    float* out = (float*)d_out;

    // workspace layout (halfs are 2B; all offsets 8B-aligned)
    __half* A16 = (__half*)d_ws;                         // N_NODES*64 f16 (38.4MB)
    __half* B16 = A16 + (size_t)N_NODES * DIM;           // 38.4MB
    __half* C16 = B16 + (size_t)N_NODES * DIM;           // 38.4MB
    uint2*  entries = (uint2*)(C16 + (size_t)N_NODES * DIM); // 5M * 8B
    int*    row_ptr = (int*)(entries + N_EDGES);         // N_NODES+1
    int*    cursor  = row_ptr + (N_NODES + 1);           // N_NODES
    int*    counts  = cursor + N_NODES;                  // N_NODES
    int*    bsums   = counts + N_NODES;                  // NBLK

    const int edge_blocks = (N_EDGES + 255) / 256;
    const int node_vec_blocks = (N_NODES * (DIM / 4) + 255) / 256;
    const int pull_blocks = (N_NODES + 3) / 4;           // 4 waves/block

    // ---- build CSR ----
    hipMemsetAsync(counts, 0, (size_t)N_NODES * sizeof(int), stream);
    hist_rows<<<edge_blocks, 256, 0, stream>>>(rows, counts);
    scan_block<<<NBLK, 256, 0, stream>>>(counts, row_ptr, bsums);
    scan_sums<<<1, 256, 0, stream>>>(bsums, NBLK);
    finalize_rowptr<<<NBLK, 256, 0, stream>>>(row_ptr, bsums, cursor);
    fill_csr<<<edge_blocks, 256, 0, stream>>>(rows, cols, ew, cursor, entries);

    // ---- layer-0 fp16 snapshot ----
    init_f16<<<node_vec_blocks, 256, 0, stream>>>(
        (const float4*)user_w, (const float4*)item_w, (uint2*)A16);

    // ---- 3 propagation layers (fp16 ping-pong, no acc RMW) ----
    pull16<<<pull_blocks, 256, 0, stream>>>(A16, B16, row_ptr, entries); // L1=B16
    pull16<<<pull_blocks, 256, 0, stream>>>(B16, C16, row_ptr, entries); // L2=C16
    pull16<<<pull_blocks, 256, 0, stream>>>(C16, A16, row_ptr, entries); // L3=A16

    // ---- out = (layer0 + L1 + L2 + L3)/4 ----
    final_combine<<<node_vec_blocks, 256, 0, stream>>>(
        (const float4*)user_w, (const float4*)item_w,
        (const uint2*)B16, (const uint2*)C16, (const uint2*)A16, (float4*)out);
}

// Round 4
// 1159.705 us; speedup vs baseline: 11.0035x; 1.0461x over previous
//
#include <hip/hip_runtime.h>
#include <hip/hip_fp16.h>

#define N_USERS 200000
#define N_ITEMS 100000
#define N_NODES 300000   // N_USERS + N_ITEMS
#define DIM 64
#define N_EDGES 5000000

#define BROWS 64                              // rows per bucket
#define NB ((N_NODES + BROWS - 1) / BROWS)    // 4688 buckets
#define NPART 8                               // block-parity partitions per bucket
#define NC (NB * NPART)                       // 37504 (bucket,part) counters
#define SCAN_BLOCKS ((NC + 255) / 256)        // 147
#define COL_MASK ((1u << 26) - 1)

// ---------------------------------------------------------------------------
// step 1: histogram of (bucket, partition).  partition = blockIdx & 7 so the
// same edge->counter mapping is reproduced by bin_fill.
// ---------------------------------------------------------------------------
__global__ void hist_bins(const int* __restrict__ rows, int* __restrict__ bcnt) {
    int e = blockIdx.x * 256 + threadIdx.x;
    if (e >= N_EDGES) return;
    int p = blockIdx.x & (NPART - 1);
    int b = rows[e] >> 6;
    atomicAdd(&bcnt[b * NPART + p], 1);
}

// ---------------------------------------------------------------------------
// generic 3-phase exclusive scan over n counters
// ---------------------------------------------------------------------------
__global__ void scan_block_g(const int* __restrict__ in, int* __restrict__ out,
                             int* __restrict__ bsums, int n) {
    __shared__ int s[256];
    int i = blockIdx.x * 256 + threadIdx.x;
    int v = (i < n) ? in[i] : 0;
    s[threadIdx.x] = v;
    __syncthreads();
    for (int off = 1; off < 256; off <<= 1) {
        int t = (threadIdx.x >= off) ? s[threadIdx.x - off] : 0;
        __syncthreads();
        s[threadIdx.x] += t;
        __syncthreads();
    }
    if (i < n) out[i] = s[threadIdx.x] - v;     // exclusive within block
    if (threadIdx.x == 255) bsums[blockIdx.x] = s[255];
}

__global__ void scan_sums_g(int* __restrict__ bsums, int nb) {
    __shared__ int s[256];
    __shared__ int carry;
    if (threadIdx.x == 0) carry = 0;
    __syncthreads();
    for (int base = 0; base < nb; base += 256) {
        int i = base + threadIdx.x;
        int v = (i < nb) ? bsums[i] : 0;
        s[threadIdx.x] = v;
        __syncthreads();
        for (int off = 1; off < 256; off <<= 1) {
            int t = (threadIdx.x >= off) ? s[threadIdx.x - off] : 0;
            __syncthreads();
            s[threadIdx.x] += t;
            __syncthreads();
        }
        if (i < nb) bsums[i] = carry + s[threadIdx.x] - v;
        __syncthreads();
        if (threadIdx.x == 255) carry += s[255];
        __syncthreads();
    }
}

// add block offsets; copy to cursor; set sentinels
__global__ void finalize_g(int* __restrict__ boff, const int* __restrict__ bsums,
                           int* __restrict__ bcur, int* __restrict__ row_ptr) {
    int i = blockIdx.x * 256 + threadIdx.x;
    if (i < NC) {
        int v = boff[i] + bsums[blockIdx.x];
        boff[i] = v;
        bcur[i] = v;
    }
    if (i == 0) {
        boff[NC] = N_EDGES;
        row_ptr[N_NODES] = N_EDGES;
    }
}

// ---------------------------------------------------------------------------
// step 2: bin edges into (bucket, partition) regions.  Writes within a
// sub-bucket are append-order -> cache lines get densely covered.
// Entry: x = (localrow << 26) | col, y = weight bits.
// ---------------------------------------------------------------------------
__global__ void bin_fill(const int* __restrict__ rows, const int* __restrict__ cols,
                         const float* __restrict__ w,
                         int* __restrict__ bcur, uint2* __restrict__ ent1) {
    int e = blockIdx.x * 256 + threadIdx.x;
    if (e >= N_EDGES) return;
    int p = blockIdx.x & (NPART - 1);
    int r = rows[e];
    int pos = atomicAdd(&bcur[(r >> 6) * NPART + p], 1);
    ent1[pos] = make_uint2(((unsigned)(r & 63) << 26) | (unsigned)cols[e],
                           __float_as_uint(w[e]));
}

// ---------------------------------------------------------------------------
// step 3: one workgroup per bucket — count 64 local rows, scan, scatter into
// the bucket's own contiguous region of ent2 (row-sorted), emit row_ptr.
// All reads/writes stay within ~8.5KB of this bucket -> single-XCD L2.
// ---------------------------------------------------------------------------
__global__ void sort_buckets(const uint2* __restrict__ ent1, uint2* __restrict__ ent2,
                             const int* __restrict__ boff, int* __restrict__ row_ptr) {
    __shared__ int cnt[BROWS];
    __shared__ int cur[BROWS];
    int b = blockIdx.x;
    int tid = threadIdx.x;
    int beg = boff[b * NPART];
    int end = boff[b * NPART + NPART];   // contiguous: bucket-major counter order

    if (tid < BROWS) cnt[tid] = 0;
    __syncthreads();
    for (int i = beg + tid; i < end; i += 256)
        atomicAdd(&cnt[ent1[i].x >> 26], 1);
    __syncthreads();
    if (tid == 0) {                      // exclusive scan of 64 counts
        int acc = 0;
        for (int r = 0; r < BROWS; ++r) { int c = cnt[r]; cnt[r] = acc; acc += c; }
    }
    __syncthreads();
    int row0 = b * BROWS;
    if (tid < BROWS && row0 + tid < N_NODES) {
        int base = beg + cnt[tid];
        row_ptr[row0 + tid] = base;
        cur[tid] = base;
    }
    __syncthreads();
    for (int i = beg + tid; i < end; i += 256) {
        uint2 e = ent1[i];
        int pos = atomicAdd(&cur[e.x >> 26], 1);
        ent2[pos] = make_uint2(e.x & COL_MASK, e.y);
    }
}

// ---------------------------------------------------------------------------
// init: out(f32) = concat(user,item) = layer-0 acc;  A16 = fp16 of same
// ---------------------------------------------------------------------------
__global__ void init_both(const float4* __restrict__ user,
                          const float4* __restrict__ item,
                          float4* __restrict__ outv,
                          uint2* __restrict__ A16) {
    int i = blockIdx.x * blockDim.x + threadIdx.x;
    const int n = N_NODES * (DIM / 4);
    if (i >= n) return;
    const int userN = N_USERS * (DIM / 4);
    float4 v = (i < userN) ? user[i] : item[i - userN];
    outv[i] = v;
    __half2 h01 = __floats2half2_rn(v.x, v.y);
    __half2 h23 = __floats2half2_rn(v.z, v.w);
    uint2 st;
    st.x = *reinterpret_cast<unsigned*>(&h01);
    st.y = *reinterpret_cast<unsigned*>(&h23);
    A16[i] = st;
}

// ---------------------------------------------------------------------------
// pull layer, fused acc: one wave per node, lane = dim.
//   acc = sum_e w_e * f32(src[col_e][lane])
//   if (write_dst) dst[node][lane] = f16(acc)
//   out[node][lane] = (out[node][lane] + acc) * scale
// unroll-8 keeps 8 gathers in flight per wave.
// ---------------------------------------------------------------------------
__global__ void pull16f(const __half* __restrict__ src,
                        __half* __restrict__ dst,
                        const int* __restrict__ row_ptr,
                        const uint2* __restrict__ ent,
                        float* __restrict__ out,
                        float scale, int write_dst) {
    int node = blockIdx.x * (blockDim.x >> 6) + (threadIdx.x >> 6);
    int lane = threadIdx.x & 63;
    if (node >= N_NODES) return;

    int beg = row_ptr[node];
    int end = row_ptr[node + 1];

    float acc = 0.0f;
    int p = beg;
    if ((p & 1) && p < end) {            // align to 16B for uint4 entry loads
        uint2 e0 = ent[p];
        acc = fmaf(__uint_as_float(e0.y),
                   __half2float(src[(size_t)e0.x * DIM + lane]), acc);
        ++p;
    }
    for (; p + 7 < end; p += 8) {
        uint4 q0 = *reinterpret_cast<const uint4*>(&ent[p]);
        uint4 q1 = *reinterpret_cast<const uint4*>(&ent[p + 2]);
        uint4 q2 = *reinterpret_cast<const uint4*>(&ent[p + 4]);
        uint4 q3 = *reinterpret_cast<const uint4*>(&ent[p + 6]);
        float v0 = __half2float(src[(size_t)q0.x * DIM + lane]);
        float v1 = __half2float(src[(size_t)q0.z * DIM + lane]);
        float v2 = __half2float(src[(size_t)q1.x * DIM + lane]);
        float v3 = __half2float(src[(size_t)q1.z * DIM + lane]);
        float v4 = __half2float(src[(size_t)q2.x * DIM + lane]);
        float v5 = __half2float(src[(size_t)q2.z * DIM + lane]);
        float v6 = __half2float(src[(size_t)q3.x * DIM + lane]);
        float v7 = __half2float(src[(size_t)q3.z * DIM + lane]);
        acc = fmaf(__uint_as_float(q0.y), v0, acc);
        acc = fmaf(__uint_as_float(q0.w), v1, acc);
        acc = fmaf(__uint_as_float(q1.y), v2, acc);
        acc = fmaf(__uint_as_float(q1.w), v3, acc);
        acc = fmaf(__uint_as_float(q2.y), v4, acc);
        acc = fmaf(__uint_as_float(q2.w), v5, acc);
        acc = fmaf(__uint_as_float(q3.y), v6, acc);
        acc = fmaf(__uint_as_float(q3.w), v7, acc);
    }
    for (; p < end; ++p) {
        uint2 e0 = ent[p];
        acc = fmaf(__uint_as_float(e0.y),
                   __half2float(src[(size_t)e0.x * DIM + lane]), acc);
    }

    size_t oi = (size_t)node * DIM + lane;
    if (write_dst) dst[oi] = __float2half_rn(acc);
    out[oi] = (out[oi] + acc) * scale;
}

extern "C" void kernel_launch(void* const* d_in, const int* in_sizes, int n_in,
                              void* d_out, int out_size, void* d_ws, size_t ws_size,
                              hipStream_t stream) {
    const float* user_w = (const float*)d_in[0];
    const float* item_w = (const float*)d_in[1];
    const int*   eidx   = (const int*)d_in[2];
    const float* ew     = (const float*)d_in[3];

    const int* rows = eidx;             // edge_index[0] (destination)
    const int* cols = eidx + N_EDGES;   // edge_index[1] (source)

    float* out = (float*)d_out;

    // workspace layout (~158 MB)
    __half* A16   = (__half*)d_ws;                           // 38.4 MB
    __half* B16   = A16 + (size_t)N_NODES * DIM;             // 38.4 MB
    uint2*  ent1  = (uint2*)(B16 + (size_t)N_NODES * DIM);   // 40 MB (binned)
    uint2*  ent2  = ent1 + N_EDGES;                          // 40 MB (row-sorted)
    int*    boff  = (int*)(ent2 + N_EDGES);                  // NC+1
    int*    bcur  = boff + (NC + 1);                         // NC
    int*    bcnt  = bcur + NC;                               // NC
    int*    bsums = bcnt + NC;                               // SCAN_BLOCKS
    int*    row_ptr = bsums + SCAN_BLOCKS;                   // N_NODES+1

    const int edge_blocks = (N_EDGES + 255) / 256;
    const int node_vec_blocks = (N_NODES * (DIM / 4) + 255) / 256;
    const int pull_blocks = (N_NODES + 3) / 4;               // 4 waves/block

    // ---- build row-sorted CSR via bucket radix ----
    hipMemsetAsync(bcnt, 0, (size_t)NC * sizeof(int), stream);
    hist_bins<<<edge_blocks, 256, 0, stream>>>(rows, bcnt);
    scan_block_g<<<SCAN_BLOCKS, 256, 0, stream>>>(bcnt, boff, bsums, NC);
    scan_sums_g<<<1, 256, 0, stream>>>(bsums, SCAN_BLOCKS);
    finalize_g<<<SCAN_BLOCKS, 256, 0, stream>>>(boff, bsums, bcur, row_ptr);
    bin_fill<<<edge_blocks, 256, 0, stream>>>(rows, cols, ew, bcur, ent1);
    sort_buckets<<<NB, 256, 0, stream>>>(ent1, ent2, boff, row_ptr);

    // ---- init: out = layer0 (f32), A16 = fp16(layer0) ----
    init_both<<<node_vec_blocks, 256, 0, stream>>>(
        (const float4*)user_w, (const float4*)item_w, (float4*)out, (uint2*)A16);

    // ---- 3 pull layers, acc fused into out ----
    pull16f<<<pull_blocks, 256, 0, stream>>>(A16, B16, row_ptr, ent2, out, 1.0f, 1);
    pull16f<<<pull_blocks, 256, 0, stream>>>(B16, A16, row_ptr, ent2, out, 1.0f, 1);
    pull16f<<<pull_blocks, 256, 0, stream>>>(A16, B16, row_ptr, ent2, out, 0.25f, 0);
}